// Round 1
// baseline (13018.367 us; speedup 1.0000x reference)
//
#include <hip/hip_runtime.h>
#include <hip/hip_bf16.h>
#include <cstddef>

#define VV   49408
#define D    512
#define H    8
#define NL   12
#define FFD  2048
#define BZ   128
#define TT   69
#define NP   8
#define DGD  6
#define DSD  6
#define SS   77            // TT + NP
#define MM   (BZ*SS)       // 9856
#define HD   64            // D/H
#define EPSV 1e-5f
#define NEGV (-3.402823466e38f)
#define SCALEV 0.125f

// ---------------- embed: x[b,s,:] = src + pos_emb[s] ----------------
__global__ void embed_kernel(const int* __restrict__ tok,
                             const float* __restrict__ g_prompt,
                             const float* __restrict__ token_emb,
                             const float* __restrict__ pos_emb,
                             float* __restrict__ x) {
    int bs = blockIdx.x;            // 0..MM-1
    int b = bs / SS, s = bs % SS;
    const float* src;
    if (s == 0)           src = token_emb + (size_t)tok[b*TT] * D;
    else if (s <= NP)     src = g_prompt + (((size_t)b*DGD + 0)*NP + (s-1))*D;
    else                  src = token_emb + (size_t)tok[b*TT + (s - NP)] * D;
    const float4* s4 = (const float4*)src;
    const float4* p4 = (const float4*)(pos_emb + (size_t)s*D);
    float4* d4 = (float4*)(x + (size_t)bs*D);
    int t = threadIdx.x;            // 128 threads, D/4 = 128 float4
    float4 a = s4[t], p = p4[t];
    a.x += p.x; a.y += p.y; a.z += p.z; a.w += p.w;
    d4[t] = a;
}

// ---------------- prompt swap for layer i>0 (no pos emb) ----------------
__global__ void set_prompt_kernel(const float* __restrict__ prompt, int li,
                                  float* __restrict__ x) {
    int bp = blockIdx.x;            // b*NP + p
    int b = bp >> 3, p = bp & 7;
    const float4* s4 = (const float4*)(prompt + (((size_t)b*DGD + li)*NP + p)*D);
    float4* d4 = (float4*)(x + ((size_t)(b*SS) + 1 + p)*D);
    d4[threadIdx.x] = s4[threadIdx.x];
}

// ---------------- wave-per-row layernorm helper ----------------
__device__ inline void ln_wave(float4 a0, float4 a1,
                               const float* __restrict__ g, const float* __restrict__ bb,
                               float* __restrict__ dst, int lane) {
    float s = a0.x+a0.y+a0.z+a0.w + a1.x+a1.y+a1.z+a1.w;
    #pragma unroll
    for (int off = 1; off < 64; off <<= 1) s += __shfl_xor(s, off, 64);
    float mean = s * (1.f/512.f);
    float dx, q = 0.f;
    dx=a0.x-mean; q+=dx*dx; dx=a0.y-mean; q+=dx*dx; dx=a0.z-mean; q+=dx*dx; dx=a0.w-mean; q+=dx*dx;
    dx=a1.x-mean; q+=dx*dx; dx=a1.y-mean; q+=dx*dx; dx=a1.z-mean; q+=dx*dx; dx=a1.w-mean; q+=dx*dx;
    #pragma unroll
    for (int off = 1; off < 64; off <<= 1) q += __shfl_xor(q, off, 64);
    float inv = rsqrtf(q*(1.f/512.f) + EPSV);
    const float4* g4 = (const float4*)g; const float4* b4 = (const float4*)bb;
    float4 g0 = g4[lane], g1 = g4[lane+64], c0 = b4[lane], c1 = b4[lane+64];
    float4 r0, r1;
    r0.x = (a0.x-mean)*inv*g0.x + c0.x;  r0.y = (a0.y-mean)*inv*g0.y + c0.y;
    r0.z = (a0.z-mean)*inv*g0.z + c0.z;  r0.w = (a0.w-mean)*inv*g0.w + c0.w;
    r1.x = (a1.x-mean)*inv*g1.x + c1.x;  r1.y = (a1.y-mean)*inv*g1.y + c1.y;
    r1.z = (a1.z-mean)*inv*g1.z + c1.z;  r1.w = (a1.w-mean)*inv*g1.w + c1.w;
    ((float4*)dst)[lane] = r0; ((float4*)dst)[lane+64] = r1;
}

__global__ __launch_bounds__(256) void ln_kernel(const float* __restrict__ x,
                                                 const float* __restrict__ g,
                                                 const float* __restrict__ bb,
                                                 float* __restrict__ out) {
    int row  = blockIdx.x*4 + (threadIdx.x >> 6);
    int lane = threadIdx.x & 63;
    const float4* x4 = (const float4*)(x + (size_t)row*D);
    float4 a0 = x4[lane], a1 = x4[lane+64];
    ln_wave(a0, a1, g, bb, out + (size_t)row*D, lane);
}

// ---------------- fp32 tiled GEMM: C[M,N] = A[M,K] @ W[K,N] (+bias, epilogue) ----
// EPI 0: (acc+bias)*scale   EPI 1: res + acc + bias   EPI 2: gelu-silu(acc+bias)
template<int EPI>
__global__ __launch_bounds__(256) void gemm_kernel(
    const float* __restrict__ A, const float* __restrict__ W,
    const float* __restrict__ bias, const float* __restrict__ res,
    float* __restrict__ C, int N, int K, float scale)
{
    __shared__ float As[16][68];   // [k][m], padded
    __shared__ float Ws[16][64];   // [k][n]
    int tx = threadIdx.x, ty = threadIdx.y;     // 16x16
    int t = ty*16 + tx;
    int m0 = blockIdx.y*64, n0 = blockIdx.x*64;
    float acc[4][4] = {};
    int ar = t >> 2;               // 0..63  (A tile row)
    int ac = (t & 3) << 2;         // 0,4,8,12 (A tile k base)
    int wr = t >> 4;               // 0..15  (W tile k)
    int wc = (t & 15) << 2;        // 0..60  (W tile n base)
    for (int k0 = 0; k0 < K; k0 += 16) {
        float4 av = *(const float4*)&A[(size_t)(m0+ar)*K + k0 + ac];
        float4 wv = *(const float4*)&W[(size_t)(k0+wr)*N + n0 + wc];
        As[ac+0][ar] = av.x; As[ac+1][ar] = av.y; As[ac+2][ar] = av.z; As[ac+3][ar] = av.w;
        *(float4*)&Ws[wr][wc] = wv;
        __syncthreads();
        #pragma unroll
        for (int kk = 0; kk < 16; kk++) {
            float4 am = *(const float4*)&As[kk][ty*4];
            float4 wm = *(const float4*)&Ws[kk][tx*4];
            float a_[4] = {am.x, am.y, am.z, am.w};
            float w_[4] = {wm.x, wm.y, wm.z, wm.w};
            #pragma unroll
            for (int i = 0; i < 4; i++)
                #pragma unroll
                for (int j = 0; j < 4; j++)
                    acc[i][j] += a_[i] * w_[j];
        }
        __syncthreads();
    }
    const float4 bv4 = *(const float4*)&bias[n0 + tx*4];
    float barr[4] = {bv4.x, bv4.y, bv4.z, bv4.w};
    #pragma unroll
    for (int i = 0; i < 4; i++) {
        int r = m0 + ty*4 + i;
        float4 o4;
        float vals[4];
        #pragma unroll
        for (int j = 0; j < 4; j++) {
            float val = acc[i][j] + barr[j];
            if (EPI == 0) val *= scale;
            else if (EPI == 2) val = val / (1.f + expf(-1.702f * val));
            vals[j] = val;
        }
        if (EPI == 1) {
            float4 r4 = *(const float4*)&res[(size_t)r*N + n0 + tx*4];
            vals[0] += r4.x; vals[1] += r4.y; vals[2] += r4.z; vals[3] += r4.w;
        }
        o4.x = vals[0]; o4.y = vals[1]; o4.z = vals[2]; o4.w = vals[3];
        *(float4*)&C[(size_t)r*N + n0 + tx*4] = o4;
    }
}

// ---------------- fused attention per (b, head) ----------------
#define SPAD 65
__global__ __launch_bounds__(256) void attn_kernel(
    const float* __restrict__ q, const float* __restrict__ k,
    const float* __restrict__ v, const int* __restrict__ amask,
    float* __restrict__ o)
{
    __shared__ float qs[SS][SPAD], ks[SS][SPAD], vs[SS][SPAD];
    __shared__ float padb[SS];
    int bh = blockIdx.x; int b = bh >> 3, hh = bh & 7;
    int t = threadIdx.x, wave = t >> 6, lane = t & 63;
    size_t base = ((size_t)b * SS) * D + hh * HD;
    for (int idx = t; idx < SS*HD; idx += 256) {
        int s = idx >> 6, d = idx & 63;
        size_t gi = base + (size_t)s*D + d;
        qs[s][d] = q[gi]; ks[s][d] = k[gi]; vs[s][d] = v[gi];
    }
    if (t < SS) padb[t] = (t < NP) ? 0.f : (amask[b*TT + t - NP] ? 0.f : NEGV);
    __syncthreads();
    for (int sq = wave; sq < SS; sq += 4) {
        int sk0 = lane, sk1 = lane + 64;
        int sk1c = (sk1 < SS) ? sk1 : 0;
        float acc0 = 0.f, acc1 = 0.f;
        #pragma unroll 8
        for (int d = 0; d < HD; d++) {
            float qv = qs[sq][d];
            acc0 += qv * ks[sk0][d];
            acc1 += qv * ks[sk1c][d];
        }
        float s0 = acc0 + padb[sk0] + ((sk0 > sq) ? NEGV : 0.f);
        float s1 = (sk1 < SS) ? (acc1 + padb[sk1] + ((sk1 > sq) ? NEGV : 0.f)) : -INFINITY;
        float mx = fmaxf(s0, s1);
        #pragma unroll
        for (int off = 1; off < 64; off <<= 1) mx = fmaxf(mx, __shfl_xor(mx, off, 64));
        float e0 = expf(s0 - mx);
        float e1 = (sk1 < SS) ? expf(s1 - mx) : 0.f;
        float sm = e0 + e1;
        #pragma unroll
        for (int off = 1; off < 64; off <<= 1) sm += __shfl_xor(sm, off, 64);
        float inv = 1.f / sm;
        float p0 = e0 * inv, p1 = e1 * inv;
        float oacc = 0.f;
        for (int sk = 0; sk <= sq; sk++) {     // p==0 exactly for sk>sq (causal)
            float pv = (sk < 64) ? __shfl(p0, sk, 64) : __shfl(p1, sk - 64, 64);
            oacc += pv * vs[sk][lane];
        }
        o[((size_t)b*SS + sq)*D + hh*HD + lane] = oacc;
    }
}

// ---------------- final: argmax -> LN -> gather ----------------
__global__ void final_kernel(const int* __restrict__ tok, const float* __restrict__ x,
                             const float* __restrict__ g, const float* __restrict__ bb,
                             float* __restrict__ out)
{
    int b = blockIdx.x, lane = threadIdx.x;   // 64 threads
    int myv = -2147483647 - 1, myi = 0x7fffffff;
    for (int tt = lane; tt < TT; tt += 64) {
        int vv2 = tok[b*TT + tt];
        if (vv2 > myv) { myv = vv2; myi = tt; }
    }
    #pragma unroll
    for (int off = 1; off < 64; off <<= 1) {
        int ov = __shfl_xor(myv, off, 64);
        int oi = __shfl_xor(myi, off, 64);
        if (ov > myv || (ov == myv && oi < myi)) { myv = ov; myi = oi; }
    }
    int pos = myi + NP;
    const float4* x4 = (const float4*)(x + ((size_t)b*SS + pos)*D);
    float4 a0 = x4[lane], a1 = x4[lane+64];
    ln_wave(a0, a1, g, bb, out + (size_t)b*D, lane);
}

extern "C" void kernel_launch(void* const* d_in, const int* in_sizes, int n_in,
                              void* d_out, int out_size, void* d_ws, size_t ws_size,
                              hipStream_t stream) {
    const int*   tok      = (const int*)d_in[0];
    const int*   amask    = (const int*)d_in[1];
    const float* g_prompt = (const float*)d_in[2];
    const float* s_prompt = (const float*)d_in[3];
    const float* token_emb= (const float*)d_in[4];
    const float* pos_emb  = (const float*)d_in[5];
    const float* ln1_g    = (const float*)d_in[6];
    const float* ln1_b    = (const float*)d_in[7];
    const float* Wq = (const float*)d_in[8];
    const float* bq = (const float*)d_in[9];
    const float* Wk = (const float*)d_in[10];
    const float* bk = (const float*)d_in[11];
    const float* Wv = (const float*)d_in[12];
    const float* bv = (const float*)d_in[13];
    const float* Wo = (const float*)d_in[14];
    const float* bo = (const float*)d_in[15];
    const float* ln2_g = (const float*)d_in[16];
    const float* ln2_b = (const float*)d_in[17];
    const float* W1 = (const float*)d_in[18];
    const float* b1 = (const float*)d_in[19];
    const float* W2 = (const float*)d_in[20];
    const float* b2 = (const float*)d_in[21];
    const float* lnf_g = (const float*)d_in[22];
    const float* lnf_b = (const float*)d_in[23];
    float* out = (float*)d_out;

    // workspace: x | h | scratch(M*FF) with q,k,v aliased into scratch
    float* x  = (float*)d_ws;
    float* h  = x + (size_t)MM*D;
    float* sc = h + (size_t)MM*D;              // MM*FFD floats
    float* qb = sc;
    float* kb = sc + (size_t)MM*D;
    float* vb = sc + 2*(size_t)MM*D;
    float* ff = sc;

    dim3 g512(512/64, MM/64), gff(FFD/64, MM/64), blk(16,16);

    embed_kernel<<<MM, 128, 0, stream>>>(tok, g_prompt, token_emb, pos_emb, x);
    for (int i = 0; i < NL; i++) {
        if (i > 0) {
            const float* pr = (i < DGD) ? g_prompt : s_prompt;
            int li = (i < DGD) ? i : i - (NL - DSD);
            set_prompt_kernel<<<BZ*NP, 128, 0, stream>>>(pr, li, x);
        }
        ln_kernel<<<MM/4, 256, 0, stream>>>(x, ln1_g + i*D, ln1_b + i*D, h);
        gemm_kernel<0><<<g512, blk, 0, stream>>>(h, Wq + (size_t)i*D*D, bq + i*D, nullptr, qb, 512, 512, SCALEV);
        gemm_kernel<0><<<g512, blk, 0, stream>>>(h, Wk + (size_t)i*D*D, bk + i*D, nullptr, kb, 512, 512, 1.f);
        gemm_kernel<0><<<g512, blk, 0, stream>>>(h, Wv + (size_t)i*D*D, bv + i*D, nullptr, vb, 512, 512, 1.f);
        attn_kernel<<<BZ*H, 256, 0, stream>>>(qb, kb, vb, amask, h);   // h <- attention out
        gemm_kernel<1><<<g512, blk, 0, stream>>>(h, Wo + (size_t)i*D*D, bo + i*D, x, x, 512, 512, 1.f);
        ln_kernel<<<MM/4, 256, 0, stream>>>(x, ln2_g + i*D, ln2_b + i*D, h);
        gemm_kernel<2><<<gff, blk, 0, stream>>>(h, W1 + (size_t)i*D*FFD, b1 + i*FFD, nullptr, ff, FFD, 512, 1.f);
        gemm_kernel<1><<<g512, blk, 0, stream>>>(ff, W2 + (size_t)i*FFD*D, b2 + i*D, x, x, 512, FFD, 1.f);
    }
    final_kernel<<<BZ, 64, 0, stream>>>(tok, x, lnf_g, lnf_b, out);
}

// Round 2
// 4775.506 us; speedup vs baseline: 2.7261x; 2.7261x over previous
//
#include <hip/hip_runtime.h>
#include <hip/hip_bf16.h>
#include <cstddef>
#include <cstdint>

#define D    512
#define H    8
#define NL   12
#define FFD  2048
#define BZ   128
#define TT   69
#define NP   8
#define DGD  6
#define DSD  6
#define SS   77            // TT + NP
#define MM   (BZ*SS)       // 9856
#define HD   64            // D/H
#define EPSV 1e-5f
#define NEGV (-3.402823466e38f)
#define SCALEV 0.125f
#define NQKV 1536

typedef __attribute__((ext_vector_type(8))) short short8;
typedef __attribute__((ext_vector_type(4))) float floatx4;

__device__ inline unsigned short bfb(float f) {
    __hip_bfloat16 h = __float2bfloat16(f);
    return *reinterpret_cast<unsigned short*>(&h);
}

__device__ inline void gload_lds16(const void* g, void* l) {
    __builtin_amdgcn_global_load_lds((const __attribute__((address_space(1))) void*)g,
                                     (__attribute__((address_space(3))) void*)l, 16, 0, 0);
}

// ---------------- embed: x[b,s,:] = src + pos_emb[s] (fp32) ----------------
__global__ void embed_kernel(const int* __restrict__ tok,
                             const float* __restrict__ g_prompt,
                             const float* __restrict__ token_emb,
                             const float* __restrict__ pos_emb,
                             float* __restrict__ x) {
    int bs = blockIdx.x;
    int b = bs / SS, s = bs % SS;
    const float* src;
    if (s == 0)           src = token_emb + (size_t)tok[b*TT] * D;
    else if (s <= NP)     src = g_prompt + (((size_t)b*DGD + 0)*NP + (s-1))*D;
    else                  src = token_emb + (size_t)tok[b*TT + (s - NP)] * D;
    const float4* s4 = (const float4*)src;
    const float4* p4 = (const float4*)(pos_emb + (size_t)s*D);
    float4* d4 = (float4*)(x + (size_t)bs*D);
    int t = threadIdx.x;
    float4 a = s4[t], p = p4[t];
    a.x += p.x; a.y += p.y; a.z += p.z; a.w += p.w;
    d4[t] = a;
}

// ---------------- prompt swap for layer i>0 ----------------
__global__ void set_prompt_kernel(const float* __restrict__ prompt, int li,
                                  float* __restrict__ x) {
    int bp = blockIdx.x;
    int b = bp >> 3, p = bp & 7;
    const float4* s4 = (const float4*)(prompt + (((size_t)b*DGD + li)*NP + p)*D);
    float4* d4 = (float4*)(x + ((size_t)(b*SS) + 1 + p)*D);
    d4[threadIdx.x] = s4[threadIdx.x];
}

// ---------------- weight transpose+convert: out[n][k] = in[k][n]*scale (bf16) ----
__global__ __launch_bounds__(256) void convert_T(const float* __restrict__ in,
                                                 unsigned short* __restrict__ out,
                                                 int K, int N,
                                                 long inLS, long outLS, float scale) {
    __shared__ float t[32][33];
    int n0 = blockIdx.x*32, k0 = blockIdx.y*32, z = blockIdx.z;
    in  += (long)z * inLS;
    out += (long)z * outLS;
    int tx = threadIdx.x & 31, ty = threadIdx.x >> 5;   // 32 x 8
    #pragma unroll
    for (int r = 0; r < 4; r++)
        t[ty + r*8][tx] = in[(long)(k0 + ty + r*8)*N + n0 + tx];
    __syncthreads();
    #pragma unroll
    for (int r = 0; r < 4; r++)
        out[(long)(n0 + ty + r*8)*K + k0 + tx] = bfb(t[tx][ty + r*8] * scale);
}

// ---------------- pack qkv biases (scale folded into q) ----------------
__global__ void pack_bias(const float* __restrict__ bq, const float* __restrict__ bk,
                          const float* __restrict__ bv, float* __restrict__ outb) {
    int i = blockIdx.x*256 + threadIdx.x;      // NL*1536
    int z = i / NQKV, c = i % NQKV;
    float v;
    if (c < 512)       v = bq[z*512 + c] * SCALEV;
    else if (c < 1024) v = bk[z*512 + c - 512];
    else               v = bv[z*512 + c - 1024];
    outb[i] = v;
}

// ---------------- layernorm -> bf16 out ----------------
__global__ __launch_bounds__(256) void ln_bf16_kernel(const float* __restrict__ x,
                                                      const float* __restrict__ g,
                                                      const float* __restrict__ bb,
                                                      unsigned short* __restrict__ out) {
    int row  = blockIdx.x*4 + (threadIdx.x >> 6);
    int lane = threadIdx.x & 63;
    const float4* x4 = (const float4*)(x + (size_t)row*D);
    float4 a0 = x4[lane], a1 = x4[lane+64];
    float s = a0.x+a0.y+a0.z+a0.w + a1.x+a1.y+a1.z+a1.w;
    #pragma unroll
    for (int off = 1; off < 64; off <<= 1) s += __shfl_xor(s, off, 64);
    float mean = s * (1.f/512.f);
    float dx, q = 0.f;
    dx=a0.x-mean; q+=dx*dx; dx=a0.y-mean; q+=dx*dx; dx=a0.z-mean; q+=dx*dx; dx=a0.w-mean; q+=dx*dx;
    dx=a1.x-mean; q+=dx*dx; dx=a1.y-mean; q+=dx*dx; dx=a1.z-mean; q+=dx*dx; dx=a1.w-mean; q+=dx*dx;
    #pragma unroll
    for (int off = 1; off < 64; off <<= 1) q += __shfl_xor(q, off, 64);
    float inv = rsqrtf(q*(1.f/512.f) + EPSV);
    const float4* g4 = (const float4*)g; const float4* b4 = (const float4*)bb;
    float4 g0 = g4[lane], g1 = g4[lane+64], c0 = b4[lane], c1 = b4[lane+64];
    unsigned short* dst = out + (size_t)row*D;
    ushort4 o0, o1;
    o0.x = bfb((a0.x-mean)*inv*g0.x + c0.x);  o0.y = bfb((a0.y-mean)*inv*g0.y + c0.y);
    o0.z = bfb((a0.z-mean)*inv*g0.z + c0.z);  o0.w = bfb((a0.w-mean)*inv*g0.w + c0.w);
    o1.x = bfb((a1.x-mean)*inv*g1.x + c1.x);  o1.y = bfb((a1.y-mean)*inv*g1.y + c1.y);
    o1.z = bfb((a1.z-mean)*inv*g1.z + c1.z);  o1.w = bfb((a1.w-mean)*inv*g1.w + c1.w);
    ((ushort4*)dst)[lane] = o0; ((ushort4*)dst)[lane+64] = o1;
}

// ---------------- bf16 MFMA GEMM: C[M,N] = A[M,K] @ Wt[N,K]^T (+bias, epilogue) ----
// EPI 0: acc+bias -> fp32     EPI 1: acc+bias+res -> fp32    EPI 2: gelu(acc+bias) -> bf16
template<int EPI, bool OBF>
__global__ __launch_bounds__(256) void mfma_gemm(
    const unsigned short* __restrict__ A, const unsigned short* __restrict__ Wt,
    const float* __restrict__ bias, const float* __restrict__ res,
    void* __restrict__ Cv, int N, int K)
{
    __shared__ unsigned short As[128*32];   // [m][k], xor-swizzled 16B units
    __shared__ unsigned short Bs[128*32];   // [n][k], xor-swizzled
    const int tid = threadIdx.x, wv = tid >> 6, ln = tid & 63;
    const int m0 = blockIdx.y*128, n0 = blockIdx.x*128;
    const int wm = (wv >> 1)*64, wn = (wv & 1)*64;
    floatx4 acc[4][4];
    #pragma unroll
    for (int i = 0; i < 4; i++)
        #pragma unroll
        for (int j = 0; j < 4; j++) acc[i][j] = (floatx4){0.f, 0.f, 0.f, 0.f};
    const int rowc = ln >> 2;                       // row within 16-row chunk
    const int uu   = (ln & 3) ^ ((ln >> 3) & 3);    // logical 16B k-unit (swizzle inverse)
    const int frow = ln & 15;
    const int fu   = (ln >> 4) ^ ((ln >> 1) & 3);   // physical 16B k-unit for frag read

    for (int kk = 0; kk < K; kk += 32) {
        #pragma unroll
        for (int c = 0; c < 2; c++) {
            const int i = wv*2 + c;
            gload_lds16(A  + (size_t)(m0 + i*16 + rowc)*K + kk + uu*8, As + i*512);
            gload_lds16(Wt + (size_t)(n0 + i*16 + rowc)*K + kk + uu*8, Bs + i*512);
        }
        __syncthreads();
        short8 af[4], bfr[4];
        #pragma unroll
        for (int mi = 0; mi < 4; mi++)
            af[mi] = *(const short8*)&As[(wm + mi*16 + frow)*32 + fu*8];
        #pragma unroll
        for (int ni = 0; ni < 4; ni++)
            bfr[ni] = *(const short8*)&Bs[(wn + ni*16 + frow)*32 + fu*8];
        #pragma unroll
        for (int mi = 0; mi < 4; mi++)
            #pragma unroll
            for (int ni = 0; ni < 4; ni++)
                acc[mi][ni] = __builtin_amdgcn_mfma_f32_16x16x32_bf16(af[mi], bfr[ni], acc[mi][ni], 0, 0, 0);
        __syncthreads();
    }

    float* Cf = (float*)Cv; unsigned short* Cb = (unsigned short*)Cv;
    const int er = m0 + wm + ((ln >> 4) << 2);
    const int ec = n0 + wn + frow;
    #pragma unroll
    for (int ni = 0; ni < 4; ni++) {
        const int col = ec + ni*16;
        const float bv = bias[col];
        #pragma unroll
        for (int mi = 0; mi < 4; mi++) {
            #pragma unroll
            for (int r = 0; r < 4; r++) {
                const int row = er + mi*16 + r;
                float v = acc[mi][ni][r] + bv;
                if (EPI == 1) v += res[(size_t)row*N + col];
                if (EPI == 2) v = v / (1.f + __expf(-1.702f*v));
                if (OBF) Cb[(size_t)row*N + col] = bfb(v);
                else     Cf[(size_t)row*N + col] = v;
            }
        }
    }
}

// ---------------- fused attention per (b, head): qkv fp32 packed, out bf16 ----------------
#define SPAD 65
__global__ __launch_bounds__(256) void attn_kernel(
    const float* __restrict__ qkv, const int* __restrict__ amask,
    unsigned short* __restrict__ o)
{
    __shared__ float qs[SS][SPAD], ks[SS][SPAD], vs[SS][SPAD];
    __shared__ float padb[SS];
    int bh = blockIdx.x; int b = bh >> 3, hh = bh & 7;
    int t = threadIdx.x, wave = t >> 6, lane = t & 63;
    size_t base = ((size_t)b * SS) * NQKV + hh * HD;
    for (int idx = t; idx < SS*HD; idx += 256) {
        int s = idx >> 6, d = idx & 63;
        size_t gi = base + (size_t)s*NQKV + d;
        qs[s][d] = qkv[gi]; ks[s][d] = qkv[gi + 512]; vs[s][d] = qkv[gi + 1024];
    }
    if (t < SS) padb[t] = (t < NP) ? 0.f : (amask[b*TT + t - NP] ? 0.f : NEGV);
    __syncthreads();
    for (int sq = wave; sq < SS; sq += 4) {
        int sk0 = lane, sk1 = lane + 64;
        int sk1c = (sk1 < SS) ? sk1 : 0;
        float acc0 = 0.f, acc1 = 0.f;
        #pragma unroll 8
        for (int d = 0; d < HD; d++) {
            float qv = qs[sq][d];
            acc0 += qv * ks[sk0][d];
            acc1 += qv * ks[sk1c][d];
        }
        float s0 = acc0 + padb[sk0] + ((sk0 > sq) ? NEGV : 0.f);
        float s1 = (sk1 < SS) ? (acc1 + padb[sk1] + ((sk1 > sq) ? NEGV : 0.f)) : -INFINITY;
        float mx = fmaxf(s0, s1);
        #pragma unroll
        for (int off = 1; off < 64; off <<= 1) mx = fmaxf(mx, __shfl_xor(mx, off, 64));
        float e0 = expf(s0 - mx);
        float e1 = (sk1 < SS) ? expf(s1 - mx) : 0.f;
        float sm = e0 + e1;
        #pragma unroll
        for (int off = 1; off < 64; off <<= 1) sm += __shfl_xor(sm, off, 64);
        float inv = 1.f / sm;
        float p0 = e0 * inv, p1 = e1 * inv;
        float oacc = 0.f;
        for (int sk = 0; sk <= sq; sk++) {
            float pv = (sk < 64) ? __shfl(p0, sk, 64) : __shfl(p1, sk - 64, 64);
            oacc += pv * vs[sk][lane];
        }
        o[((size_t)b*SS + sq)*D + hh*HD + lane] = bfb(oacc);
    }
}

// ---------------- final: argmax -> LN -> gather (fp32 out) ----------------
__global__ void final_kernel(const int* __restrict__ tok, const float* __restrict__ x,
                             const float* __restrict__ g, const float* __restrict__ bb,
                             float* __restrict__ out)
{
    int b = blockIdx.x, lane = threadIdx.x;
    int myv = -2147483647 - 1, myi = 0x7fffffff;
    for (int tt = lane; tt < TT; tt += 64) {
        int vv2 = tok[b*TT + tt];
        if (vv2 > myv) { myv = vv2; myi = tt; }
    }
    #pragma unroll
    for (int off = 1; off < 64; off <<= 1) {
        int ov = __shfl_xor(myv, off, 64);
        int oi = __shfl_xor(myi, off, 64);
        if (ov > myv || (ov == myv && oi < myi)) { myv = ov; myi = oi; }
    }
    int pos = myi + NP;
    const float4* x4 = (const float4*)(x + ((size_t)b*SS + pos)*D);
    float4 a0 = x4[lane], a1 = x4[lane+64];
    float s = a0.x+a0.y+a0.z+a0.w + a1.x+a1.y+a1.z+a1.w;
    #pragma unroll
    for (int off = 1; off < 64; off <<= 1) s += __shfl_xor(s, off, 64);
    float mean = s * (1.f/512.f);
    float dx, q = 0.f;
    dx=a0.x-mean; q+=dx*dx; dx=a0.y-mean; q+=dx*dx; dx=a0.z-mean; q+=dx*dx; dx=a0.w-mean; q+=dx*dx;
    dx=a1.x-mean; q+=dx*dx; dx=a1.y-mean; q+=dx*dx; dx=a1.z-mean; q+=dx*dx; dx=a1.w-mean; q+=dx*dx;
    #pragma unroll
    for (int off = 1; off < 64; off <<= 1) q += __shfl_xor(q, off, 64);
    float inv = rsqrtf(q*(1.f/512.f) + EPSV);
    const float4* g4 = (const float4*)g; const float4* b4 = (const float4*)bb;
    float4 g0 = g4[lane], g1 = g4[lane+64], c0 = b4[lane], c1 = b4[lane+64];
    float* dst = out + (size_t)b*D;
    float4 r0, r1;
    r0.x = (a0.x-mean)*inv*g0.x + c0.x;  r0.y = (a0.y-mean)*inv*g0.y + c0.y;
    r0.z = (a0.z-mean)*inv*g0.z + c0.z;  r0.w = (a0.w-mean)*inv*g0.w + c0.w;
    r1.x = (a1.x-mean)*inv*g1.x + c1.x;  r1.y = (a1.y-mean)*inv*g1.y + c1.y;
    r1.z = (a1.z-mean)*inv*g1.z + c1.z;  r1.w = (a1.w-mean)*inv*g1.w + c1.w;
    ((float4*)dst)[lane] = r0; ((float4*)dst)[lane+64] = r1;
}

extern "C" void kernel_launch(void* const* d_in, const int* in_sizes, int n_in,
                              void* d_out, int out_size, void* d_ws, size_t ws_size,
                              hipStream_t stream) {
    const int*   tok      = (const int*)d_in[0];
    const int*   amask    = (const int*)d_in[1];
    const float* g_prompt = (const float*)d_in[2];
    const float* s_prompt = (const float*)d_in[3];
    const float* token_emb= (const float*)d_in[4];
    const float* pos_emb  = (const float*)d_in[5];
    const float* ln1_g    = (const float*)d_in[6];
    const float* ln1_b    = (const float*)d_in[7];
    const float* Wq = (const float*)d_in[8];
    const float* bq = (const float*)d_in[9];
    const float* Wk = (const float*)d_in[10];
    const float* bk = (const float*)d_in[11];
    const float* Wv = (const float*)d_in[12];
    const float* bv = (const float*)d_in[13];
    const float* Wo = (const float*)d_in[14];
    const float* bo = (const float*)d_in[15];
    const float* ln2_g = (const float*)d_in[16];
    const float* ln2_b = (const float*)d_in[17];
    const float* W1 = (const float*)d_in[18];
    const float* b1 = (const float*)d_in[19];
    const float* W2 = (const float*)d_in[20];
    const float* b2 = (const float*)d_in[21];
    const float* lnf_g = (const float*)d_in[22];
    const float* lnf_b = (const float*)d_in[23];
    float* out = (float*)d_out;

    // ---- workspace carve (bytes) ----
    char* p = (char*)d_ws;
    float* x = (float*)p;                 p += (size_t)MM*D*4;
    float* qkv = (float*)p;               // MM*1536 fp32; ff (bf16, MM*FFD*2) aliases
    unsigned short* ff = (unsigned short*)qkv;
    p += (size_t)MM*NQKV*4;
    unsigned short* h = (unsigned short*)p;      p += (size_t)MM*D*2;
    unsigned short* WqkvT = (unsigned short*)p;  p += (size_t)NL*NQKV*D*2;
    unsigned short* WoT   = (unsigned short*)p;  p += (size_t)NL*D*D*2;
    unsigned short* W1T   = (unsigned short*)p;  p += (size_t)NL*FFD*D*2;
    unsigned short* W2T   = (unsigned short*)p;  p += (size_t)NL*D*FFD*2;
    float* bqkv = (float*)p;                     p += (size_t)NL*NQKV*4;

    // ---- weight conversion (every call; inputs re-poisoned-safe, read-only) ----
    convert_T<<<dim3(16, 16, NL), 256, 0, stream>>>(Wq, WqkvT,                     512, 512, (long)512*512,  (long)NQKV*512, SCALEV);
    convert_T<<<dim3(16, 16, NL), 256, 0, stream>>>(Wk, WqkvT + (size_t)512*512,   512, 512, (long)512*512,  (long)NQKV*512, 1.f);
    convert_T<<<dim3(16, 16, NL), 256, 0, stream>>>(Wv, WqkvT + (size_t)1024*512,  512, 512, (long)512*512,  (long)NQKV*512, 1.f);
    convert_T<<<dim3(16, 16, NL), 256, 0, stream>>>(Wo, WoT,                       512, 512, (long)512*512,  (long)512*512,  1.f);
    convert_T<<<dim3(FFD/32, 16, NL), 256, 0, stream>>>(W1, W1T,                   512, FFD, (long)512*FFD,  (long)FFD*512,  1.f);
    convert_T<<<dim3(16, FFD/32, NL), 256, 0, stream>>>(W2, W2T,                   FFD, 512, (long)FFD*512,  (long)512*FFD,  1.f);
    pack_bias<<<NL*NQKV/256, 256, 0, stream>>>(bq, bk, bv, bqkv);

    embed_kernel<<<MM, 128, 0, stream>>>(tok, g_prompt, token_emb, pos_emb, x);
    for (int i = 0; i < NL; i++) {
        if (i > 0) {
            const float* pr = (i < DGD) ? g_prompt : s_prompt;
            int li = (i < DGD) ? i : i - (NL - DSD);
            set_prompt_kernel<<<BZ*NP, 128, 0, stream>>>(pr, li, x);
        }
        ln_bf16_kernel<<<MM/4, 256, 0, stream>>>(x, ln1_g + i*D, ln1_b + i*D, h);
        mfma_gemm<0,false><<<dim3(NQKV/128, MM/128), 256, 0, stream>>>(
            h, WqkvT + (size_t)i*NQKV*D, bqkv + i*NQKV, nullptr, qkv, NQKV, D);
        attn_kernel<<<BZ*H, 256, 0, stream>>>(qkv, amask, h);
        mfma_gemm<1,false><<<dim3(D/128, MM/128), 256, 0, stream>>>(
            h, WoT + (size_t)i*D*D, bo + i*D, x, x, D, D);
        ln_bf16_kernel<<<MM/4, 256, 0, stream>>>(x, ln2_g + i*D, ln2_b + i*D, h);
        mfma_gemm<2,true><<<dim3(FFD/128, MM/128), 256, 0, stream>>>(
            h, W1T + (size_t)i*FFD*D, b1 + i*FFD, nullptr, ff, FFD, D);
        mfma_gemm<1,false><<<dim3(D/128, MM/128), 256, 0, stream>>>(
            ff, W2T + (size_t)i*D*FFD, b2 + i*D, x, x, D, FFD);
    }
    final_kernel<<<BZ, 64, 0, stream>>>(tok, x, lnf_g, lnf_b, out);
}

// Round 3
// 2623.765 us; speedup vs baseline: 4.9617x; 1.8201x over previous
//
#include <hip/hip_runtime.h>
#include <hip/hip_bf16.h>
#include <cstddef>
#include <cstdint>

#define D    512
#define H    8
#define NL   12
#define FFD  2048
#define BZ   128
#define TT   69
#define NP   8
#define DGD  6
#define DSD  6
#define SS   77            // TT + NP
#define MM   (BZ*SS)       // 9856
#define HD   64            // D/H
#define EPSV 1e-5f
#define NEGV (-3.402823466e38f)
#define SCALEV 0.125f
#define NQKV 1536

typedef __attribute__((ext_vector_type(8))) short short8;
typedef __attribute__((ext_vector_type(4))) float floatx4;

__device__ inline unsigned short bfb(float f) {
    __hip_bfloat16 h = __float2bfloat16(f);
    return *reinterpret_cast<unsigned short*>(&h);
}

__device__ inline void gload_lds16(const void* g, void* l) {
    __builtin_amdgcn_global_load_lds((const __attribute__((address_space(1))) void*)g,
                                     (__attribute__((address_space(3))) void*)l, 16, 0, 0);
}

// ---------------- embed: x[b,s,:] = src + pos_emb[s] (fp32) ----------------
__global__ void embed_kernel(const int* __restrict__ tok,
                             const float* __restrict__ g_prompt,
                             const float* __restrict__ token_emb,
                             const float* __restrict__ pos_emb,
                             float* __restrict__ x) {
    int bs = blockIdx.x;
    int b = bs / SS, s = bs % SS;
    const float* src;
    if (s == 0)           src = token_emb + (size_t)tok[b*TT] * D;
    else if (s <= NP)     src = g_prompt + (((size_t)b*DGD + 0)*NP + (s-1))*D;
    else                  src = token_emb + (size_t)tok[b*TT + (s - NP)] * D;
    const float4* s4 = (const float4*)src;
    const float4* p4 = (const float4*)(pos_emb + (size_t)s*D);
    float4* d4 = (float4*)(x + (size_t)bs*D);
    int t = threadIdx.x;
    float4 a = s4[t], p = p4[t];
    a.x += p.x; a.y += p.y; a.z += p.z; a.w += p.w;
    d4[t] = a;
}

// ---------------- prompt swap for layer i>0 ----------------
__global__ void set_prompt_kernel(const float* __restrict__ prompt, int li,
                                  float* __restrict__ x) {
    int bp = blockIdx.x;
    int b = bp >> 3, p = bp & 7;
    const float4* s4 = (const float4*)(prompt + (((size_t)b*DGD + li)*NP + p)*D);
    float4* d4 = (float4*)(x + ((size_t)(b*SS) + 1 + p)*D);
    d4[threadIdx.x] = s4[threadIdx.x];
}

// ---------------- weight transpose+convert: out[n][k] = in[k][n]*scale (bf16) ----
__global__ __launch_bounds__(256) void convert_T(const float* __restrict__ in,
                                                 unsigned short* __restrict__ out,
                                                 int K, int N,
                                                 long inLS, long outLS, float scale) {
    __shared__ float t[32][33];
    int n0 = blockIdx.x*32, k0 = blockIdx.y*32, z = blockIdx.z;
    in  += (long)z * inLS;
    out += (long)z * outLS;
    int tx = threadIdx.x & 31, ty = threadIdx.x >> 5;   // 32 x 8
    #pragma unroll
    for (int r = 0; r < 4; r++)
        t[ty + r*8][tx] = in[(long)(k0 + ty + r*8)*N + n0 + tx];
    __syncthreads();
    #pragma unroll
    for (int r = 0; r < 4; r++)
        out[(long)(n0 + ty + r*8)*K + k0 + tx] = bfb(t[tx][ty + r*8] * scale);
}

// ---------------- pack qkv biases (scale folded into q) ----------------
__global__ void pack_bias(const float* __restrict__ bq, const float* __restrict__ bk,
                          const float* __restrict__ bv, float* __restrict__ outb) {
    int i = blockIdx.x*256 + threadIdx.x;      // NL*1536
    int z = i / NQKV, c = i % NQKV;
    float v;
    if (c < 512)       v = bq[z*512 + c] * SCALEV;
    else if (c < 1024) v = bk[z*512 + c - 512];
    else               v = bv[z*512 + c - 1024];
    outb[i] = v;
}

// ---------------- layernorm -> bf16 out ----------------
__global__ __launch_bounds__(256) void ln_bf16_kernel(const float* __restrict__ x,
                                                      const float* __restrict__ g,
                                                      const float* __restrict__ bb,
                                                      unsigned short* __restrict__ out) {
    int row  = blockIdx.x*4 + (threadIdx.x >> 6);
    int lane = threadIdx.x & 63;
    const float4* x4 = (const float4*)(x + (size_t)row*D);
    float4 a0 = x4[lane], a1 = x4[lane+64];
    float s = a0.x+a0.y+a0.z+a0.w + a1.x+a1.y+a1.z+a1.w;
    #pragma unroll
    for (int off = 1; off < 64; off <<= 1) s += __shfl_xor(s, off, 64);
    float mean = s * (1.f/512.f);
    float dx, q = 0.f;
    dx=a0.x-mean; q+=dx*dx; dx=a0.y-mean; q+=dx*dx; dx=a0.z-mean; q+=dx*dx; dx=a0.w-mean; q+=dx*dx;
    dx=a1.x-mean; q+=dx*dx; dx=a1.y-mean; q+=dx*dx; dx=a1.z-mean; q+=dx*dx; dx=a1.w-mean; q+=dx*dx;
    #pragma unroll
    for (int off = 1; off < 64; off <<= 1) q += __shfl_xor(q, off, 64);
    float inv = rsqrtf(q*(1.f/512.f) + EPSV);
    const float4* g4 = (const float4*)g; const float4* b4 = (const float4*)bb;
    float4 g0 = g4[lane], g1 = g4[lane+64], c0 = b4[lane], c1 = b4[lane+64];
    unsigned short* dst = out + (size_t)row*D;
    ushort4 o0, o1;
    o0.x = bfb((a0.x-mean)*inv*g0.x + c0.x);  o0.y = bfb((a0.y-mean)*inv*g0.y + c0.y);
    o0.z = bfb((a0.z-mean)*inv*g0.z + c0.z);  o0.w = bfb((a0.w-mean)*inv*g0.w + c0.w);
    o1.x = bfb((a1.x-mean)*inv*g1.x + c1.x);  o1.y = bfb((a1.y-mean)*inv*g1.y + c1.y);
    o1.z = bfb((a1.z-mean)*inv*g1.z + c1.z);  o1.w = bfb((a1.w-mean)*inv*g1.w + c1.w);
    ((ushort4*)dst)[lane] = o0; ((ushort4*)dst)[lane+64] = o1;
}

// ---------------- bf16 MFMA GEMM: C[M,N] = A[M,K] @ Wt[N,K]^T (+bias, epilogue) ----
// EPI 0: acc+bias -> fp32     EPI 1: acc+bias+res -> fp32    EPI 2: gelu(acc+bias) -> bf16
template<int EPI, bool OBF>
__global__ __launch_bounds__(256) void mfma_gemm(
    const unsigned short* __restrict__ A, const unsigned short* __restrict__ Wt,
    const float* __restrict__ bias, const float* __restrict__ res,
    void* __restrict__ Cv, int N, int K)
{
    __shared__ unsigned short As[128*32];   // [m][k], xor-swizzled 16B units
    __shared__ unsigned short Bs[128*32];   // [n][k], xor-swizzled
    const int tid = threadIdx.x, wv = tid >> 6, ln = tid & 63;
    const int m0 = blockIdx.y*128, n0 = blockIdx.x*128;
    const int wm = (wv >> 1)*64, wn = (wv & 1)*64;
    floatx4 acc[4][4];
    #pragma unroll
    for (int i = 0; i < 4; i++)
        #pragma unroll
        for (int j = 0; j < 4; j++) acc[i][j] = (floatx4){0.f, 0.f, 0.f, 0.f};
    const int rowc = ln >> 2;                       // row within 16-row chunk
    const int uu   = (ln & 3) ^ ((ln >> 3) & 3);    // logical 16B k-unit (swizzle inverse)
    const int frow = ln & 15;
    const int fu   = (ln >> 4) ^ ((ln >> 1) & 3);   // physical 16B k-unit for frag read

    for (int kk = 0; kk < K; kk += 32) {
        #pragma unroll
        for (int c = 0; c < 2; c++) {
            const int i = wv*2 + c;
            gload_lds16(A  + (size_t)(m0 + i*16 + rowc)*K + kk + uu*8, As + i*512);
            gload_lds16(Wt + (size_t)(n0 + i*16 + rowc)*K + kk + uu*8, Bs + i*512);
        }
        __syncthreads();
        short8 af[4], bfr[4];
        #pragma unroll
        for (int mi = 0; mi < 4; mi++)
            af[mi] = *(const short8*)&As[(wm + mi*16 + frow)*32 + fu*8];
        #pragma unroll
        for (int ni = 0; ni < 4; ni++)
            bfr[ni] = *(const short8*)&Bs[(wn + ni*16 + frow)*32 + fu*8];
        #pragma unroll
        for (int mi = 0; mi < 4; mi++)
            #pragma unroll
            for (int ni = 0; ni < 4; ni++)
                acc[mi][ni] = __builtin_amdgcn_mfma_f32_16x16x32_bf16(af[mi], bfr[ni], acc[mi][ni], 0, 0, 0);
        __syncthreads();
    }

    float* Cf = (float*)Cv; unsigned short* Cb = (unsigned short*)Cv;
    const int er = m0 + wm + ((ln >> 4) << 2);
    const int ec = n0 + wn + frow;
    #pragma unroll
    for (int ni = 0; ni < 4; ni++) {
        const int col = ec + ni*16;
        const float bv = bias[col];
        #pragma unroll
        for (int mi = 0; mi < 4; mi++) {
            #pragma unroll
            for (int r = 0; r < 4; r++) {
                const int row = er + mi*16 + r;
                float v = acc[mi][ni][r] + bv;
                if (EPI == 1) v += res[(size_t)row*N + col];
                if (EPI == 2) v = v / (1.f + __expf(-1.702f*v));
                if (OBF) Cb[(size_t)row*N + col] = bfb(v);
                else     Cf[(size_t)row*N + col] = v;
            }
        }
    }
}

// ---------------- MFMA flash attention, one (b,h) per block ----------------
// S padded 77->80 (5 tiles), HD=64 (2 ksteps for QK, 4 d-tiles; PV K padded to 96).
// Frag-ready LDS layouts: unit (tile, kstep, lane) at ((tile*KS + kstep)*64 + lane)*8 ushorts.
__global__ __launch_bounds__(256) void attn_mfma_kernel(
    const float* __restrict__ qkv, const int* __restrict__ amask,
    unsigned short* __restrict__ o)
{
    __shared__ unsigned short Qf[5*2*64*8];   // 10 KB
    __shared__ unsigned short Kf[5*2*64*8];   // 10 KB
    __shared__ unsigned short Vf[4*3*64*8];   // 12 KB  [dt][ks][lane]: V[k=sk][n=d]
    __shared__ unsigned short Pf[4*3*64*8];   // 12 KB  per-wave A-frag P

    const int bh = blockIdx.x, b = bh >> 3, hh = bh & 7;
    const int tid = threadIdx.x, wv = tid >> 6, ln = tid & 63;
    const int cl = ln & 15, qd = ln >> 4;
    const float* qb = qkv + (size_t)b*SS*NQKV + hh*HD;
    const float* kb = qb + 512;
    const float* vb = qb + 1024;

    // ---- stage Q,K in frag layout: unit u -> tile t=u>>7, ks=(u>>6)&1, lane l=u&63
    for (int u = tid; u < 640; u += 256) {
        int t = u >> 7, ks = (u >> 6) & 1, l = u & 63;
        int row = t*16 + (l & 15), c0 = ks*32 + (l >> 4)*8;
        short8 uq, uk;
        if (row < SS) {
            const float* sq2 = qb + (size_t)row*NQKV + c0;
            const float* sk2 = kb + (size_t)row*NQKV + c0;
            float4 q0 = *(const float4*)sq2, q1 = *(const float4*)(sq2 + 4);
            float4 k0 = *(const float4*)sk2, k1 = *(const float4*)(sk2 + 4);
            uq[0]=(short)bfb(q0.x); uq[1]=(short)bfb(q0.y); uq[2]=(short)bfb(q0.z); uq[3]=(short)bfb(q0.w);
            uq[4]=(short)bfb(q1.x); uq[5]=(short)bfb(q1.y); uq[6]=(short)bfb(q1.z); uq[7]=(short)bfb(q1.w);
            uk[0]=(short)bfb(k0.x); uk[1]=(short)bfb(k0.y); uk[2]=(short)bfb(k0.z); uk[3]=(short)bfb(k0.w);
            uk[4]=(short)bfb(k1.x); uk[5]=(short)bfb(k1.y); uk[6]=(short)bfb(k1.z); uk[7]=(short)bfb(k1.w);
        } else {
            uq = (short8){0,0,0,0,0,0,0,0};
            uk = (short8){0,0,0,0,0,0,0,0};
        }
        *(short8*)&Qf[u*8] = uq;
        *(short8*)&Kf[u*8] = uk;
    }
    // ---- stage V transposed into B-frag layout: element (s,d) -> [d>>4][s>>5][((s>>3)&3)*16+(d&15)] j=s&7
    for (int u = tid; u < SS*16; u += 256) {
        int s = u >> 4, d0 = (u & 15)*4;
        float4 vv = *(const float4*)(vb + (size_t)s*NQKV + d0);
        int ksv = s >> 5, fq = (s >> 3) & 3, j = s & 7;
        float va[4] = {vv.x, vv.y, vv.z, vv.w};
        #pragma unroll
        for (int e = 0; e < 4; e++) {
            int d = d0 + e;
            Vf[(((d >> 4)*3 + ksv)*64 + fq*16 + (d & 15))*8 + j] = bfb(va[e]);
        }
    }
    // zero V tail (s = 77..95)
    for (int u = tid; u < 19*64; u += 256) {
        int s = SS + (u >> 6), d = u & 63;
        int ksv = s >> 5, fq = (s >> 3) & 3, j = s & 7;
        Vf[(((d >> 4)*3 + ksv)*64 + fq*16 + (d & 15))*8 + j] = 0;
    }
    // zero P tail for this wave (cols 80..95 -> ks=2, frag-lanes 32..63)
    {
        int base = wv*1536 + 2*64*8 + 32*8;
        for (int u = ln; u < 256; u += 64) Pf[base + u] = 0;
    }
    // pad-mask bias per lane's columns
    float padc[5];
    #pragma unroll
    for (int nt = 0; nt < 5; nt++) {
        int col = nt*16 + cl;
        padc[nt] = (col >= SS) ? NEGV
                 : ((col < NP) ? 0.f : (amask[b*TT + col - NP] ? 0.f : NEGV));
    }
    __syncthreads();

    const int pbase = wv*1536;
    for (int mt = wv; mt < 5; mt += 4) {
        // ---- QK^T: S-tile row mt over 5 col-tiles
        short8 qf0 = *(const short8*)&Qf[((mt*2 + 0)*64 + ln)*8];
        short8 qf1 = *(const short8*)&Qf[((mt*2 + 1)*64 + ln)*8];
        float p[5][4];
        #pragma unroll
        for (int nt = 0; nt < 5; nt++) {
            short8 kf0 = *(const short8*)&Kf[((nt*2 + 0)*64 + ln)*8];
            short8 kf1 = *(const short8*)&Kf[((nt*2 + 1)*64 + ln)*8];
            floatx4 a = (floatx4){0.f, 0.f, 0.f, 0.f};
            a = __builtin_amdgcn_mfma_f32_16x16x32_bf16(qf0, kf0, a, 0, 0, 0);
            a = __builtin_amdgcn_mfma_f32_16x16x32_bf16(qf1, kf1, a, 0, 0, 0);
            #pragma unroll
            for (int r = 0; r < 4; r++) p[nt][r] = a[r];
        }
        // ---- bias + softmax (rows distributed: row = mt*16 + qd*4 + r, col = nt*16 + cl)
        #pragma unroll
        for (int r = 0; r < 4; r++) {
            int row = mt*16 + qd*4 + r;
            float mx = -INFINITY;
            #pragma unroll
            for (int nt = 0; nt < 5; nt++) {
                int col = nt*16 + cl;
                float sv = p[nt][r] + padc[nt] + ((col > row) ? NEGV : 0.f);
                p[nt][r] = sv;
                mx = fmaxf(mx, sv);
            }
            #pragma unroll
            for (int off = 1; off < 16; off <<= 1) mx = fmaxf(mx, __shfl_xor(mx, off, 64));
            float sum = 0.f;
            #pragma unroll
            for (int nt = 0; nt < 5; nt++) {
                float e = __expf(p[nt][r] - mx);
                p[nt][r] = e; sum += e;
            }
            #pragma unroll
            for (int off = 1; off < 16; off <<= 1) sum += __shfl_xor(sum, off, 64);
            float inv = 1.f / sum;
            #pragma unroll
            for (int nt = 0; nt < 5; nt++) p[nt][r] *= inv;
        }
        // ---- write P into per-wave A-frag LDS region (bf16)
        #pragma unroll
        for (int nt = 0; nt < 5; nt++) {
            int c = nt*16 + cl;
            int ksf = c >> 5, flh = (c >> 3) & 3, j = c & 7;
            #pragma unroll
            for (int r = 0; r < 4; r++)
                Pf[pbase + (ksf*64 + flh*16 + qd*4 + r)*8 + j] = bfb(p[nt][r]);
        }
        // ---- P @ V (same-wave LDS RAW; compiler inserts lgkmcnt waits)
        short8 pf0 = *(const short8*)&Pf[pbase + (0*64 + ln)*8];
        short8 pf1 = *(const short8*)&Pf[pbase + (1*64 + ln)*8];
        short8 pf2 = *(const short8*)&Pf[pbase + (2*64 + ln)*8];
        #pragma unroll
        for (int dt = 0; dt < 4; dt++) {
            floatx4 oacc = (floatx4){0.f, 0.f, 0.f, 0.f};
            short8 vf0 = *(const short8*)&Vf[((dt*3 + 0)*64 + ln)*8];
            short8 vf1 = *(const short8*)&Vf[((dt*3 + 1)*64 + ln)*8];
            short8 vf2 = *(const short8*)&Vf[((dt*3 + 2)*64 + ln)*8];
            oacc = __builtin_amdgcn_mfma_f32_16x16x32_bf16(pf0, vf0, oacc, 0, 0, 0);
            oacc = __builtin_amdgcn_mfma_f32_16x16x32_bf16(pf1, vf1, oacc, 0, 0, 0);
            oacc = __builtin_amdgcn_mfma_f32_16x16x32_bf16(pf2, vf2, oacc, 0, 0, 0);
            #pragma unroll
            for (int r = 0; r < 4; r++) {
                int sq = mt*16 + qd*4 + r;
                if (sq < SS)
                    o[((size_t)b*SS + sq)*D + hh*HD + dt*16 + cl] = bfb(oacc[r]);
            }
        }
    }
}

// ---------------- final: argmax -> LN -> gather (fp32 out) ----------------
__global__ void final_kernel(const int* __restrict__ tok, const float* __restrict__ x,
                             const float* __restrict__ g, const float* __restrict__ bb,
                             float* __restrict__ out)
{
    int b = blockIdx.x, lane = threadIdx.x;
    int myv = -2147483647 - 1, myi = 0x7fffffff;
    for (int tt = lane; tt < TT; tt += 64) {
        int vv2 = tok[b*TT + tt];
        if (vv2 > myv) { myv = vv2; myi = tt; }
    }
    #pragma unroll
    for (int off = 1; off < 64; off <<= 1) {
        int ov = __shfl_xor(myv, off, 64);
        int oi = __shfl_xor(myi, off, 64);
        if (ov > myv || (ov == myv && oi < myi)) { myv = ov; myi = oi; }
    }
    int pos = myi + NP;
    const float4* x4 = (const float4*)(x + ((size_t)b*SS + pos)*D);
    float4 a0 = x4[lane], a1 = x4[lane+64];
    float s = a0.x+a0.y+a0.z+a0.w + a1.x+a1.y+a1.z+a1.w;
    #pragma unroll
    for (int off = 1; off < 64; off <<= 1) s += __shfl_xor(s, off, 64);
    float mean = s * (1.f/512.f);
    float dx, q = 0.f;
    dx=a0.x-mean; q+=dx*dx; dx=a0.y-mean; q+=dx*dx; dx=a0.z-mean; q+=dx*dx; dx=a0.w-mean; q+=dx*dx;
    dx=a1.x-mean; q+=dx*dx; dx=a1.y-mean; q+=dx*dx; dx=a1.z-mean; q+=dx*dx; dx=a1.w-mean; q+=dx*dx;
    #pragma unroll
    for (int off = 1; off < 64; off <<= 1) q += __shfl_xor(q, off, 64);
    float inv = rsqrtf(q*(1.f/512.f) + EPSV);
    const float4* g4 = (const float4*)g; const float4* b4 = (const float4*)bb;
    float4 g0 = g4[lane], g1 = g4[lane+64], c0 = b4[lane], c1 = b4[lane+64];
    float* dst = out + (size_t)b*D;
    float4 r0, r1;
    r0.x = (a0.x-mean)*inv*g0.x + c0.x;  r0.y = (a0.y-mean)*inv*g0.y + c0.y;
    r0.z = (a0.z-mean)*inv*g0.z + c0.z;  r0.w = (a0.w-mean)*inv*g0.w + c0.w;
    r1.x = (a1.x-mean)*inv*g1.x + c1.x;  r1.y = (a1.y-mean)*inv*g1.y + c1.y;
    r1.z = (a1.z-mean)*inv*g1.z + c1.z;  r1.w = (a1.w-mean)*inv*g1.w + c1.w;
    ((float4*)dst)[lane] = r0; ((float4*)dst)[lane+64] = r1;
}

extern "C" void kernel_launch(void* const* d_in, const int* in_sizes, int n_in,
                              void* d_out, int out_size, void* d_ws, size_t ws_size,
                              hipStream_t stream) {
    const int*   tok      = (const int*)d_in[0];
    const int*   amask    = (const int*)d_in[1];
    const float* g_prompt = (const float*)d_in[2];
    const float* s_prompt = (const float*)d_in[3];
    const float* token_emb= (const float*)d_in[4];
    const float* pos_emb  = (const float*)d_in[5];
    const float* ln1_g    = (const float*)d_in[6];
    const float* ln1_b    = (const float*)d_in[7];
    const float* Wq = (const float*)d_in[8];
    const float* bq = (const float*)d_in[9];
    const float* Wk = (const float*)d_in[10];
    const float* bk = (const float*)d_in[11];
    const float* Wv = (const float*)d_in[12];
    const float* bv = (const float*)d_in[13];
    const float* Wo = (const float*)d_in[14];
    const float* bo = (const float*)d_in[15];
    const float* ln2_g = (const float*)d_in[16];
    const float* ln2_b = (const float*)d_in[17];
    const float* W1 = (const float*)d_in[18];
    const float* b1 = (const float*)d_in[19];
    const float* W2 = (const float*)d_in[20];
    const float* b2 = (const float*)d_in[21];
    const float* lnf_g = (const float*)d_in[22];
    const float* lnf_b = (const float*)d_in[23];
    float* out = (float*)d_out;

    // ---- workspace carve (bytes) ----
    char* p = (char*)d_ws;
    float* x = (float*)p;                 p += (size_t)MM*D*4;
    float* qkv = (float*)p;               // MM*1536 fp32; ff (bf16, MM*FFD*2) aliases
    unsigned short* ff = (unsigned short*)qkv;
    p += (size_t)MM*NQKV*4;
    unsigned short* h = (unsigned short*)p;      p += (size_t)MM*D*2;
    unsigned short* WqkvT = (unsigned short*)p;  p += (size_t)NL*NQKV*D*2;
    unsigned short* WoT   = (unsigned short*)p;  p += (size_t)NL*D*D*2;
    unsigned short* W1T   = (unsigned short*)p;  p += (size_t)NL*FFD*D*2;
    unsigned short* W2T   = (unsigned short*)p;  p += (size_t)NL*D*FFD*2;
    float* bqkv = (float*)p;                     p += (size_t)NL*NQKV*4;

    // ---- weight conversion (every call; inputs read-only) ----
    convert_T<<<dim3(16, 16, NL), 256, 0, stream>>>(Wq, WqkvT,                     512, 512, (long)512*512,  (long)NQKV*512, SCALEV);
    convert_T<<<dim3(16, 16, NL), 256, 0, stream>>>(Wk, WqkvT + (size_t)512*512,   512, 512, (long)512*512,  (long)NQKV*512, 1.f);
    convert_T<<<dim3(16, 16, NL), 256, 0, stream>>>(Wv, WqkvT + (size_t)1024*512,  512, 512, (long)512*512,  (long)NQKV*512, 1.f);
    convert_T<<<dim3(16, 16, NL), 256, 0, stream>>>(Wo, WoT,                       512, 512, (long)512*512,  (long)512*512,  1.f);
    convert_T<<<dim3(FFD/32, 16, NL), 256, 0, stream>>>(W1, W1T,                   512, FFD, (long)512*FFD,  (long)FFD*512,  1.f);
    convert_T<<<dim3(16, FFD/32, NL), 256, 0, stream>>>(W2, W2T,                   FFD, 512, (long)FFD*512,  (long)512*FFD,  1.f);
    pack_bias<<<NL*NQKV/256, 256, 0, stream>>>(bq, bk, bv, bqkv);

    embed_kernel<<<MM, 128, 0, stream>>>(tok, g_prompt, token_emb, pos_emb, x);
    for (int i = 0; i < NL; i++) {
        if (i > 0) {
            const float* pr = (i < DGD) ? g_prompt : s_prompt;
            int li = (i < DGD) ? i : i - (NL - DSD);
            set_prompt_kernel<<<BZ*NP, 128, 0, stream>>>(pr, li, x);
        }
        ln_bf16_kernel<<<MM/4, 256, 0, stream>>>(x, ln1_g + i*D, ln1_b + i*D, h);
        mfma_gemm<0,false><<<dim3(NQKV/128, MM/128), 256, 0, stream>>>(
            h, WqkvT + (size_t)i*NQKV*D, bqkv + i*NQKV, nullptr, qkv, NQKV, D);
        attn_mfma_kernel<<<BZ*H, 256, 0, stream>>>(qkv, amask, h);
        mfma_gemm<1,false><<<dim3(D/128, MM/128), 256, 0, stream>>>(
            h, WoT + (size_t)i*D*D, bo + i*D, x, x, D, D);
        ln_bf16_kernel<<<MM/4, 256, 0, stream>>>(x, ln2_g + i*D, ln2_b + i*D, h);
        mfma_gemm<2,true><<<dim3(FFD/128, MM/128), 256, 0, stream>>>(
            h, W1T + (size_t)i*FFD*D, b1 + i*FFD, nullptr, ff, FFD, D);
        mfma_gemm<1,false><<<dim3(D/128, MM/128), 256, 0, stream>>>(
            ff, W2T + (size_t)i*D*FFD, b2 + i*D, x, x, D, FFD);
    }
    final_kernel<<<BZ, 64, 0, stream>>>(tok, x, lnf_g, lnf_b, out);
}

// Round 4
// 2533.306 us; speedup vs baseline: 5.1389x; 1.0357x over previous
//
#include <hip/hip_runtime.h>
#include <hip/hip_bf16.h>
#include <cstddef>
#include <cstdint>

#define D    512
#define H    8
#define NL   12
#define FFD  2048
#define BZ   128
#define TT   69
#define NP   8
#define DGD  6
#define DSD  6
#define SS   77            // TT + NP
#define MM   (BZ*SS)       // 9856
#define HD   64            // D/H
#define EPSV 1e-5f
#define NEGV (-3.402823466e38f)
#define SCALEV 0.125f
#define NQKV 1536

typedef __attribute__((ext_vector_type(8))) short short8;
typedef __attribute__((ext_vector_type(8))) unsigned short ushort8;
typedef __attribute__((ext_vector_type(4))) float floatx4;

__device__ inline unsigned short bfb(float f) {
    __hip_bfloat16 h = __float2bfloat16(f);
    return *reinterpret_cast<unsigned short*>(&h);
}

__device__ inline void gload_lds16(const void* g, void* l) {
    __builtin_amdgcn_global_load_lds((const __attribute__((address_space(1))) void*)g,
                                     (__attribute__((address_space(3))) void*)l, 16, 0, 0);
}

// ---------------- embed: x[b,s,:] = src + pos_emb[s] (fp32) ----------------
__global__ void embed_kernel(const int* __restrict__ tok,
                             const float* __restrict__ g_prompt,
                             const float* __restrict__ token_emb,
                             const float* __restrict__ pos_emb,
                             float* __restrict__ x) {
    int bs = blockIdx.x;
    int b = bs / SS, s = bs % SS;
    const float* src;
    if (s == 0)           src = token_emb + (size_t)tok[b*TT] * D;
    else if (s <= NP)     src = g_prompt + (((size_t)b*DGD + 0)*NP + (s-1))*D;
    else                  src = token_emb + (size_t)tok[b*TT + (s - NP)] * D;
    const float4* s4 = (const float4*)src;
    const float4* p4 = (const float4*)(pos_emb + (size_t)s*D);
    float4* d4 = (float4*)(x + (size_t)bs*D);
    int t = threadIdx.x;
    float4 a = s4[t], p = p4[t];
    a.x += p.x; a.y += p.y; a.z += p.z; a.w += p.w;
    d4[t] = a;
}

// ---------------- weight transpose+convert: out[n][k] = in[k][n]*scale (bf16) ----
__global__ __launch_bounds__(256) void convert_T(const float* __restrict__ in,
                                                 unsigned short* __restrict__ out,
                                                 int K, int N,
                                                 long inLS, long outLS, float scale) {
    __shared__ float t[32][33];
    int n0 = blockIdx.x*32, k0 = blockIdx.y*32, z = blockIdx.z;
    in  += (long)z * inLS;
    out += (long)z * outLS;
    int tx = threadIdx.x & 31, ty = threadIdx.x >> 5;   // 32 x 8
    #pragma unroll
    for (int r = 0; r < 4; r++)
        t[ty + r*8][tx] = in[(long)(k0 + ty + r*8)*N + n0 + tx];
    __syncthreads();
    #pragma unroll
    for (int r = 0; r < 4; r++)
        out[(long)(n0 + ty + r*8)*K + k0 + tx] = bfb(t[tx][ty + r*8] * scale);
}

// ---------------- pack qkv biases (scale folded into q) ----------------
__global__ void pack_bias(const float* __restrict__ bq, const float* __restrict__ bk,
                          const float* __restrict__ bv, float* __restrict__ outb) {
    int i = blockIdx.x*256 + threadIdx.x;      // NL*1536
    int z = i / NQKV, c = i % NQKV;
    float v;
    if (c < 512)       v = bq[z*512 + c] * SCALEV;
    else if (c < 1024) v = bk[z*512 + c - 512];
    else               v = bv[z*512 + c - 1024];
    outb[i] = v;
}

// ---------------- layernorm -> bf16 out, optional fused prompt swap ----------------
__global__ __launch_bounds__(256) void ln_bf16_kernel(const float* x,
                                                      const float* __restrict__ g,
                                                      const float* __restrict__ bb,
                                                      unsigned short* __restrict__ out,
                                                      const float* __restrict__ prompt, int li,
                                                      float* xw) {
    int row  = blockIdx.x*4 + (threadIdx.x >> 6);
    int lane = threadIdx.x & 63;
    int b = row / SS, s = row - b*SS;
    bool isp = (prompt != nullptr) && (s >= 1) && (s <= NP);    // wave-uniform
    const float4* src4 = isp ? (const float4*)(prompt + (((size_t)b*6 + li)*NP + (s-1))*D)
                             : (const float4*)(x + (size_t)row*D);
    float4 a0 = src4[lane], a1 = src4[lane+64];
    if (isp) {   // propagate swapped prompt into residual stream
        float4* xd = (float4*)(xw + (size_t)row*D);
        xd[lane] = a0; xd[lane+64] = a1;
    }
    float ssum = a0.x+a0.y+a0.z+a0.w + a1.x+a1.y+a1.z+a1.w;
    #pragma unroll
    for (int off = 1; off < 64; off <<= 1) ssum += __shfl_xor(ssum, off, 64);
    float mean = ssum * (1.f/512.f);
    float dx, q = 0.f;
    dx=a0.x-mean; q+=dx*dx; dx=a0.y-mean; q+=dx*dx; dx=a0.z-mean; q+=dx*dx; dx=a0.w-mean; q+=dx*dx;
    dx=a1.x-mean; q+=dx*dx; dx=a1.y-mean; q+=dx*dx; dx=a1.z-mean; q+=dx*dx; dx=a1.w-mean; q+=dx*dx;
    #pragma unroll
    for (int off = 1; off < 64; off <<= 1) q += __shfl_xor(q, off, 64);
    float inv = rsqrtf(q*(1.f/512.f) + EPSV);
    const float4* g4 = (const float4*)g; const float4* b4 = (const float4*)bb;
    float4 g0 = g4[lane], g1 = g4[lane+64], c0 = b4[lane], c1 = b4[lane+64];
    unsigned short* dst = out + (size_t)row*D;
    ushort4 o0, o1;
    o0.x = bfb((a0.x-mean)*inv*g0.x + c0.x);  o0.y = bfb((a0.y-mean)*inv*g0.y + c0.y);
    o0.z = bfb((a0.z-mean)*inv*g0.z + c0.z);  o0.w = bfb((a0.w-mean)*inv*g0.w + c0.w);
    o1.x = bfb((a1.x-mean)*inv*g1.x + c1.x);  o1.y = bfb((a1.y-mean)*inv*g1.y + c1.y);
    o1.z = bfb((a1.z-mean)*inv*g1.z + c1.z);  o1.w = bfb((a1.w-mean)*inv*g1.w + c1.w);
    ((ushort4*)dst)[lane] = o0; ((ushort4*)dst)[lane+64] = o1;
}

// ---------------- bf16 MFMA GEMM with LDS-staged coalesced epilogue ----------------
// EPI 0: acc+bias     EPI 1: acc+bias+res     EPI 2: gelu-silu(acc+bias)
// OBF: output bf16 else fp32.
template<int EPI, bool OBF>
__global__ __launch_bounds__(256) void mfma_gemm(
    const unsigned short* __restrict__ A, const unsigned short* __restrict__ Wt,
    const float* __restrict__ bias, const float* __restrict__ res,
    void* __restrict__ Cv, int N, int K)
{
    __shared__ __align__(16) char smem[16896];          // max(As+Bs=16384, Cs=16896)
    unsigned short* As = (unsigned short*)smem;         // [128][32] xor-swizzled
    unsigned short* Bs = As + 128*32;
    float* Cs = (float*)smem;                           // 32 x 132 (padded) epilogue staging
    const int tid = threadIdx.x, wv = tid >> 6, ln = tid & 63;
    const int m0 = blockIdx.y*128, n0 = blockIdx.x*128;
    const int wm = (wv >> 1)*64, wn = (wv & 1)*64;
    floatx4 acc[4][4];
    #pragma unroll
    for (int i = 0; i < 4; i++)
        #pragma unroll
        for (int j = 0; j < 4; j++) acc[i][j] = (floatx4){0.f, 0.f, 0.f, 0.f};
    const int rowc = ln >> 2;                       // row within 16-row chunk
    const int uu   = (ln & 3) ^ ((ln >> 3) & 3);    // xor-swizzled 16B k-unit (store)
    const int frow = ln & 15, qd = ln >> 4;
    const int fu   = qd ^ ((ln >> 1) & 3);          // physical 16B k-unit (frag read)

    for (int kk = 0; kk < K; kk += 32) {
        #pragma unroll
        for (int c = 0; c < 2; c++) {
            const int i = wv*2 + c;
            gload_lds16(A  + (size_t)(m0 + i*16 + rowc)*K + kk + uu*8, As + i*512);
            gload_lds16(Wt + (size_t)(n0 + i*16 + rowc)*K + kk + uu*8, Bs + i*512);
        }
        __syncthreads();
        short8 af[4], bfr[4];
        #pragma unroll
        for (int mi = 0; mi < 4; mi++)
            af[mi] = *(const short8*)&As[(wm + mi*16 + frow)*32 + fu*8];
        #pragma unroll
        for (int ni = 0; ni < 4; ni++)
            bfr[ni] = *(const short8*)&Bs[(wn + ni*16 + frow)*32 + fu*8];
        #pragma unroll
        for (int mi = 0; mi < 4; mi++)
            #pragma unroll
            for (int ni = 0; ni < 4; ni++)
                acc[mi][ni] = __builtin_amdgcn_mfma_f32_16x16x32_bf16(af[mi], bfr[ni], acc[mi][ni], 0, 0, 0);
        __syncthreads();
    }

    // ---- epilogue: 4 chunks of 32 rows through LDS, coalesced vector I/O ----
    float* Cf = (float*)Cv; unsigned short* Cb = (unsigned short*)Cv;
    const int clr = (wv >> 1)*16 + qd*4;            // local row base in chunk (0..31)
    const int rcol = (tid & 31)*4;                  // read-phase column (0..124)
    const int rrow0 = tid >> 5;                     // read-phase row (0..7)
    const float4 b4v = *(const float4*)&bias[n0 + rcol];
    for (int mi = 0; mi < 4; mi++) {
        #pragma unroll
        for (int ni = 0; ni < 4; ni++)
            #pragma unroll
            for (int r = 0; r < 4; r++)
                Cs[(clr + r)*132 + wn + ni*16 + frow] = acc[mi][ni][r];
        __syncthreads();
        #pragma unroll
        for (int rr = 0; rr < 4; rr++) {
            int lr = rrow0 + rr*8;                  // 0..31
            int grow = m0 + ((lr >= 16) ? 64 : 0) + mi*16 + (lr & 15);
            float4 v4 = *(const float4*)&Cs[lr*132 + rcol];
            float vals[4] = {v4.x + b4v.x, v4.y + b4v.y, v4.z + b4v.z, v4.w + b4v.w};
            if (EPI == 1) {
                float4 r4 = *(const float4*)&res[(size_t)grow*N + n0 + rcol];
                vals[0] += r4.x; vals[1] += r4.y; vals[2] += r4.z; vals[3] += r4.w;
            }
            if (EPI == 2) {
                #pragma unroll
                for (int e = 0; e < 4; e++) vals[e] = vals[e] / (1.f + __expf(-1.702f*vals[e]));
            }
            if (OBF) {
                ushort4 o4 = {bfb(vals[0]), bfb(vals[1]), bfb(vals[2]), bfb(vals[3])};
                *(ushort4*)&Cb[(size_t)grow*N + n0 + rcol] = o4;
            } else {
                float4 o4 = {vals[0], vals[1], vals[2], vals[3]};
                *(float4*)&Cf[(size_t)grow*N + n0 + rcol] = o4;
            }
        }
        if (mi < 3) __syncthreads();
    }
}

// ---------------- MFMA flash attention, one (b,h) per block, bf16 qkv ----------------
__global__ __launch_bounds__(256) void attn_mfma_kernel(
    const unsigned short* __restrict__ qkv, const int* __restrict__ amask,
    unsigned short* __restrict__ o)
{
    __shared__ unsigned short Qf[5*2*64*8];   // 10 KB  A-frag layout
    __shared__ unsigned short Kf[5*2*64*8];   // 10 KB  B-frag layout (K as B)
    __shared__ unsigned short Vf[4*3*64*8];   // 12 KB  [dt][ks][lane] B-frag
    __shared__ unsigned short Pf[4*3*64*8];   // 12 KB  per-wave A-frag P

    const int bh = blockIdx.x, b = bh >> 3, hh = bh & 7;
    const int tid = threadIdx.x, wv = tid >> 6, ln = tid & 63;
    const int cl = ln & 15, qd = ln >> 4;
    const unsigned short* qb = qkv + (size_t)b*SS*NQKV + hh*HD;

    // ---- Q/K staging: direct global->LDS 16B units (unit u: t=u>>7, ks=(u>>6)&1, l=u&63)
    for (int ub = wv; ub < 10; ub += 4) {           // wave-uniform loop, 640 units total
        int u = ub*64 + ln;
        int t = u >> 7, ks = (u >> 6) & 1;
        int row = t*16 + (ln & 15), c0 = ks*32 + (ln >> 4)*8;
        gload_lds16(qb + (size_t)row*NQKV + c0,       Qf + ub*64*8);
        gload_lds16(qb + 512 + (size_t)row*NQKV + c0, Kf + ub*64*8);
    }
    // ---- V transpose staging: (s,d) -> [d>>4][s>>5][((s>>3)&3)*16+(d&15)] j=s&7
    for (int u = tid; u < SS*8; u += 256) {
        int s = u >> 3, d0 = (u & 7)*8;
        ushort8 vv = *(const ushort8*)(qb + 1024 + (size_t)s*NQKV + d0);
        int ksv = s >> 5, fq = (s >> 3) & 3, j = s & 7;
        #pragma unroll
        for (int e = 0; e < 8; e++) {
            int d = d0 + e;
            Vf[(((d >> 4)*3 + ksv)*64 + fq*16 + (d & 15))*8 + j] = vv[e];
        }
    }
    // zero V tail (s = 77..95)
    for (int u = tid; u < 19*64; u += 256) {
        int s = SS + (u >> 6), d = u & 63;
        int ksv = s >> 5, fq = (s >> 3) & 3, j = s & 7;
        Vf[(((d >> 4)*3 + ksv)*64 + fq*16 + (d & 15))*8 + j] = 0;
    }
    // zero P tail for this wave (cols 80..95 -> ks=2, frag-lanes 32..63)
    {
        int base = wv*1536 + 2*64*8 + 32*8;
        for (int u = ln; u < 256; u += 64) Pf[base + u] = 0;
    }
    float padc[5];
    #pragma unroll
    for (int nt = 0; nt < 5; nt++) {
        int col = nt*16 + cl;
        padc[nt] = (col >= SS) ? NEGV
                 : ((col < NP) ? 0.f : (amask[b*TT + col - NP] ? 0.f : NEGV));
    }
    __syncthreads();

    const int pbase = wv*1536;
    for (int mt = wv; mt < 5; mt += 4) {
        short8 qf0 = *(const short8*)&Qf[((mt*2 + 0)*64 + ln)*8];
        short8 qf1 = *(const short8*)&Qf[((mt*2 + 1)*64 + ln)*8];
        float p[5][4];
        #pragma unroll
        for (int nt = 0; nt < 5; nt++) {
            short8 kf0 = *(const short8*)&Kf[((nt*2 + 0)*64 + ln)*8];
            short8 kf1 = *(const short8*)&Kf[((nt*2 + 1)*64 + ln)*8];
            floatx4 a = (floatx4){0.f, 0.f, 0.f, 0.f};
            a = __builtin_amdgcn_mfma_f32_16x16x32_bf16(qf0, kf0, a, 0, 0, 0);
            a = __builtin_amdgcn_mfma_f32_16x16x32_bf16(qf1, kf1, a, 0, 0, 0);
            #pragma unroll
            for (int r = 0; r < 4; r++) p[nt][r] = a[r];
        }
        #pragma unroll
        for (int r = 0; r < 4; r++) {
            int row = mt*16 + qd*4 + r;
            float mx = -INFINITY;
            #pragma unroll
            for (int nt = 0; nt < 5; nt++) {
                int col = nt*16 + cl;
                float sv = p[nt][r] + padc[nt] + ((col > row) ? NEGV : 0.f);
                p[nt][r] = sv;
                mx = fmaxf(mx, sv);
            }
            #pragma unroll
            for (int off = 1; off < 16; off <<= 1) mx = fmaxf(mx, __shfl_xor(mx, off, 64));
            float sum = 0.f;
            #pragma unroll
            for (int nt = 0; nt < 5; nt++) {
                float e = __expf(p[nt][r] - mx);
                p[nt][r] = e; sum += e;
            }
            #pragma unroll
            for (int off = 1; off < 16; off <<= 1) sum += __shfl_xor(sum, off, 64);
            float inv = 1.f / sum;
            #pragma unroll
            for (int nt = 0; nt < 5; nt++) p[nt][r] *= inv;
        }
        #pragma unroll
        for (int nt = 0; nt < 5; nt++) {
            int c = nt*16 + cl;
            int ksf = c >> 5, flh = (c >> 3) & 3, j = c & 7;
            #pragma unroll
            for (int r = 0; r < 4; r++)
                Pf[pbase + (ksf*64 + flh*16 + qd*4 + r)*8 + j] = bfb(p[nt][r]);
        }
        short8 pf0 = *(const short8*)&Pf[pbase + (0*64 + ln)*8];
        short8 pf1 = *(const short8*)&Pf[pbase + (1*64 + ln)*8];
        short8 pf2 = *(const short8*)&Pf[pbase + (2*64 + ln)*8];
        #pragma unroll
        for (int dt = 0; dt < 4; dt++) {
            floatx4 oacc = (floatx4){0.f, 0.f, 0.f, 0.f};
            short8 vf0 = *(const short8*)&Vf[((dt*3 + 0)*64 + ln)*8];
            short8 vf1 = *(const short8*)&Vf[((dt*3 + 1)*64 + ln)*8];
            short8 vf2 = *(const short8*)&Vf[((dt*3 + 2)*64 + ln)*8];
            oacc = __builtin_amdgcn_mfma_f32_16x16x32_bf16(pf0, vf0, oacc, 0, 0, 0);
            oacc = __builtin_amdgcn_mfma_f32_16x16x32_bf16(pf1, vf1, oacc, 0, 0, 0);
            oacc = __builtin_amdgcn_mfma_f32_16x16x32_bf16(pf2, vf2, oacc, 0, 0, 0);
            #pragma unroll
            for (int r = 0; r < 4; r++) {
                int sq = mt*16 + qd*4 + r;
                if (sq < SS)
                    o[((size_t)b*SS + sq)*D + hh*HD + dt*16 + cl] = bfb(oacc[r]);
            }
        }
    }
}

// ---------------- final: argmax -> LN -> gather (fp32 out) ----------------
__global__ void final_kernel(const int* __restrict__ tok, const float* __restrict__ x,
                             const float* __restrict__ g, const float* __restrict__ bb,
                             float* __restrict__ out)
{
    int b = blockIdx.x, lane = threadIdx.x;
    int myv = -2147483647 - 1, myi = 0x7fffffff;
    for (int tt = lane; tt < TT; tt += 64) {
        int vv2 = tok[b*TT + tt];
        if (vv2 > myv) { myv = vv2; myi = tt; }
    }
    #pragma unroll
    for (int off = 1; off < 64; off <<= 1) {
        int ov = __shfl_xor(myv, off, 64);
        int oi = __shfl_xor(myi, off, 64);
        if (ov > myv || (ov == myv && oi < myi)) { myv = ov; myi = oi; }
    }
    int pos = myi + NP;
    const float4* x4 = (const float4*)(x + ((size_t)b*SS + pos)*D);
    float4 a0 = x4[lane], a1 = x4[lane+64];
    float s = a0.x+a0.y+a0.z+a0.w + a1.x+a1.y+a1.z+a1.w;
    #pragma unroll
    for (int off = 1; off < 64; off <<= 1) s += __shfl_xor(s, off, 64);
    float mean = s * (1.f/512.f);
    float dx, q = 0.f;
    dx=a0.x-mean; q+=dx*dx; dx=a0.y-mean; q+=dx*dx; dx=a0.z-mean; q+=dx*dx; dx=a0.w-mean; q+=dx*dx;
    dx=a1.x-mean; q+=dx*dx; dx=a1.y-mean; q+=dx*dx; dx=a1.z-mean; q+=dx*dx; dx=a1.w-mean; q+=dx*dx;
    #pragma unroll
    for (int off = 1; off < 64; off <<= 1) q += __shfl_xor(q, off, 64);
    float inv = rsqrtf(q*(1.f/512.f) + EPSV);
    const float4* g4 = (const float4*)g; const float4* b4 = (const float4*)bb;
    float4 g0 = g4[lane], g1 = g4[lane+64], c0 = b4[lane], c1 = b4[lane+64];
    float* dst = out + (size_t)b*D;
    float4 r0, r1;
    r0.x = (a0.x-mean)*inv*g0.x + c0.x;  r0.y = (a0.y-mean)*inv*g0.y + c0.y;
    r0.z = (a0.z-mean)*inv*g0.z + c0.z;  r0.w = (a0.w-mean)*inv*g0.w + c0.w;
    r1.x = (a1.x-mean)*inv*g1.x + c1.x;  r1.y = (a1.y-mean)*inv*g1.y + c1.y;
    r1.z = (a1.z-mean)*inv*g1.z + c1.z;  r1.w = (a1.w-mean)*inv*g1.w + c1.w;
    ((float4*)dst)[lane] = r0; ((float4*)dst)[lane+64] = r1;
}

extern "C" void kernel_launch(void* const* d_in, const int* in_sizes, int n_in,
                              void* d_out, int out_size, void* d_ws, size_t ws_size,
                              hipStream_t stream) {
    const int*   tok      = (const int*)d_in[0];
    const int*   amask    = (const int*)d_in[1];
    const float* g_prompt = (const float*)d_in[2];
    const float* s_prompt = (const float*)d_in[3];
    const float* token_emb= (const float*)d_in[4];
    const float* pos_emb  = (const float*)d_in[5];
    const float* ln1_g    = (const float*)d_in[6];
    const float* ln1_b    = (const float*)d_in[7];
    const float* Wq = (const float*)d_in[8];
    const float* bq = (const float*)d_in[9];
    const float* Wk = (const float*)d_in[10];
    const float* bk = (const float*)d_in[11];
    const float* Wv = (const float*)d_in[12];
    const float* bv = (const float*)d_in[13];
    const float* Wo = (const float*)d_in[14];
    const float* bo = (const float*)d_in[15];
    const float* ln2_g = (const float*)d_in[16];
    const float* ln2_b = (const float*)d_in[17];
    const float* W1 = (const float*)d_in[18];
    const float* b1 = (const float*)d_in[19];
    const float* W2 = (const float*)d_in[20];
    const float* b2 = (const float*)d_in[21];
    const float* lnf_g = (const float*)d_in[22];
    const float* lnf_b = (const float*)d_in[23];
    float* out = (float*)d_out;

    // ---- workspace carve (bytes) ----
    char* p = (char*)d_ws;
    float* x = (float*)p;                        p += (size_t)MM*D*4;
    unsigned short* qkv = (unsigned short*)p;    // MM*1536 bf16; ff (bf16, MM*FFD) aliases
    unsigned short* ff = qkv;
    p += (size_t)MM*FFD*2;                       // max(MM*NQKV, MM*FFD)*2 = MM*FFD*2
    unsigned short* h = (unsigned short*)p;      p += (size_t)MM*D*2;
    unsigned short* WqkvT = (unsigned short*)p;  p += (size_t)NL*NQKV*D*2;
    unsigned short* WoT   = (unsigned short*)p;  p += (size_t)NL*D*D*2;
    unsigned short* W1T   = (unsigned short*)p;  p += (size_t)NL*FFD*D*2;
    unsigned short* W2T   = (unsigned short*)p;  p += (size_t)NL*D*FFD*2;
    float* bqkv = (float*)p;                     p += (size_t)NL*NQKV*4;

    // ---- weight conversion (every call; inputs read-only) ----
    convert_T<<<dim3(16, 16, NL), 256, 0, stream>>>(Wq, WqkvT,                     512, 512, (long)512*512,  (long)NQKV*512, SCALEV);
    convert_T<<<dim3(16, 16, NL), 256, 0, stream>>>(Wk, WqkvT + (size_t)512*512,   512, 512, (long)512*512,  (long)NQKV*512, 1.f);
    convert_T<<<dim3(16, 16, NL), 256, 0, stream>>>(Wv, WqkvT + (size_t)1024*512,  512, 512, (long)512*512,  (long)NQKV*512, 1.f);
    convert_T<<<dim3(16, 16, NL), 256, 0, stream>>>(Wo, WoT,                       512, 512, (long)512*512,  (long)512*512,  1.f);
    convert_T<<<dim3(FFD/32, 16, NL), 256, 0, stream>>>(W1, W1T,                   512, FFD, (long)512*FFD,  (long)FFD*512,  1.f);
    convert_T<<<dim3(16, FFD/32, NL), 256, 0, stream>>>(W2, W2T,                   FFD, 512, (long)FFD*512,  (long)512*FFD,  1.f);
    pack_bias<<<NL*NQKV/256, 256, 0, stream>>>(bq, bk, bv, bqkv);

    embed_kernel<<<MM, 128, 0, stream>>>(tok, g_prompt, token_emb, pos_emb, x);
    for (int i = 0; i < NL; i++) {
        const float* pr = (i == 0) ? nullptr : ((i < DGD) ? g_prompt : s_prompt);
        int li = (i < DGD) ? i : i - (NL - DSD);
        ln_bf16_kernel<<<MM/4, 256, 0, stream>>>(x, ln1_g + i*D, ln1_b + i*D, h, pr, li, x);
        mfma_gemm<0,true><<<dim3(NQKV/128, MM/128), 256, 0, stream>>>(
            h, WqkvT + (size_t)i*NQKV*D, bqkv + i*NQKV, nullptr, qkv, NQKV, D);
        attn_mfma_kernel<<<BZ*H, 256, 0, stream>>>(qkv, amask, h);
        mfma_gemm<1,false><<<dim3(D/128, MM/128), 256, 0, stream>>>(
            h, WoT + (size_t)i*D*D, bo + i*D, x, x, D, D);
        ln_bf16_kernel<<<MM/4, 256, 0, stream>>>(x, ln2_g + i*D, ln2_b + i*D, h, nullptr, 0, x);
        mfma_gemm<2,true><<<dim3(FFD/128, MM/128), 256, 0, stream>>>(
            h, W1T + (size_t)i*FFD*D, b1 + i*FFD, nullptr, ff, FFD, D);
        mfma_gemm<1,false><<<dim3(D/128, MM/128), 256, 0, stream>>>(
            ff, W2T + (size_t)i*D*FFD, b2 + i*D, x, x, D, FFD);
    }
    final_kernel<<<BZ, 64, 0, stream>>>(tok, x, lnf_g, lnf_b, out);
}